// Round 1
// baseline (451.917 us; speedup 1.0000x reference)
//
#include <hip/hip_runtime.h>
#include <hip/hip_bf16.h>

#define M_DIM 8192
#define N_DIM 4096
#define K_DIM 4096

typedef __bf16 bf16x8 __attribute__((ext_vector_type(8)));
typedef float f32x4 __attribute__((ext_vector_type(4)));
typedef unsigned short ushort8v __attribute__((ext_vector_type(8)));

typedef const __attribute__((address_space(1))) void gv_t;
typedef __attribute__((address_space(3))) void lv_t;

// round-to-nearest-even fp32 -> bf16 (inputs are finite; no NaN handling needed)
static __device__ __forceinline__ unsigned short f2bf(float f) {
  unsigned u = __builtin_bit_cast(unsigned, f);
  u += 0x7fffu + ((u >> 16) & 1u);
  return (unsigned short)(u >> 16);
}

// ---------------- pre-pass 1: inverse permutation ----------------
__global__ void k_pinv(const int* __restrict__ ci, int* __restrict__ pinv) {
  int k = blockIdx.x * 256 + threadIdx.x;
  if (k < K_DIM) pinv[ci[k]] = k;
}

// ---------------- pre-pass 2: x fp32 -> bf16 (streaming) ----------------
__global__ void k_cvt(const float* __restrict__ x, unsigned short* __restrict__ xb) {
  const long n4 = (long)M_DIM * K_DIM / 4;   // 8388608
  for (long i = (long)blockIdx.x * 256 + threadIdx.x; i < n4; i += 2048L * 256) {
    float4 v = *(const float4*)(x + i * 4);
    ushort4 o;
    o.x = f2bf(v.x); o.y = f2bf(v.y); o.z = f2bf(v.z); o.w = f2bf(v.w);
    *(ushort4*)(xb + i * 4) = o;
  }
}

// ---------------- pre-pass 3: dequant + permute + transpose ----------------
// out: w2t[n][c] = (float)w[pinv[c]][n] * scales[pinv[c]>>7][n]  as bf16, [N][K]
__global__ void k_w2t(const int* __restrict__ w, const float* __restrict__ scales,
                      const int* __restrict__ pinv, unsigned short* __restrict__ w2t) {
  __shared__ int tile[64 * 68];   // 64 c-rows x 64 n-cols, pitch 68 ints
  __shared__ int grp[64];
  __shared__ int krow[64];
  const int n0 = blockIdx.x * 64;
  const int c0 = blockIdx.y * 64;
  const int t = threadIdx.x;
  if (t < 64) {
    int kk = pinv[c0 + t];
    krow[t] = kk;
    grp[t] = kk >> 7;
  }
  __syncthreads();
  {
    const int ci = t >> 2, q = t & 3;
    const int kk = krow[ci];
    const int* src = w + (long)kk * N_DIM + n0 + q * 16;
#pragma unroll
    for (int j = 0; j < 4; ++j) {
      int4 v = *(const int4*)(src + j * 4);
      *(int4*)&tile[ci * 68 + q * 16 + j * 4] = v;
    }
  }
  __syncthreads();
  {
    const int nj = t >> 2, cq = t & 3;
    const int n = n0 + nj;
    unsigned short outv[16];
#pragma unroll
    for (int i = 0; i < 16; ++i) {
      int cii = cq * 16 + i;
      float f = (float)tile[cii * 68 + nj] * scales[grp[cii] * N_DIM + n];
      outv[i] = f2bf(f);
    }
    unsigned short* dst = w2t + (long)n * K_DIM + c0 + cq * 16;
    *(ushort8v*)(dst)     = *(ushort8v*)&outv[0];
    *(ushort8v*)(dst + 8) = *(ushort8v*)&outv[8];
  }
}

// ---------------- main GEMM: C[M][N] = A[M][K](bf16) * BtT + bias ----------------
// Bt is [N][K] bf16. 128x128 tile, BK=32, 4 waves, 16x16x32 bf16 MFMA.
#define BM 128
#define BN 128
#define BK 32

__global__ __launch_bounds__(256) void k_gemm(const unsigned short* __restrict__ A,
                                              const unsigned short* __restrict__ Bt,
                                              const float* __restrict__ bias,
                                              float* __restrict__ C) {
  __shared__ __attribute__((aligned(16))) unsigned short As[BM * BK];
  __shared__ __attribute__((aligned(16))) unsigned short Bs[BN * BK];

  // bijective XCD-aware swizzle: 2048 blocks, 8 XCDs
  const int bid = blockIdx.x;
  const int swz = (bid & 7) * 256 + (bid >> 3);
  const int bx = swz & 31;   // N tile (32 of them)
  const int by = swz >> 5;   // M tile (64 of them)

  const int tid = threadIdx.x;
  const int w = tid >> 6, l = tid & 63;
  const int wr = w >> 1, wc = w & 1;

  // staging map: lds byte off = w*2048 + i*1024 + l*16  <->  row = w*32+i*16+(l>>2), kbyte=(l&3)*16
  const int r0 = w * 32 + (l >> 2);
  const int kof = (l & 3) * 8;            // elements
  const int ldsoff = w * 2048 + l * 16;   // bytes

  // fragment read map
  const int lrow = l & 15;
  const int lkb = (l >> 4) * 16;          // bytes

  const int abase = (by * BM) * K_DIM;
  const int bbase = (bx * BN) * K_DIM;

  f32x4 acc[4][4];
  const f32x4 z = {0.f, 0.f, 0.f, 0.f};
#pragma unroll
  for (int mi = 0; mi < 4; ++mi)
#pragma unroll
    for (int ni = 0; ni < 4; ++ni) acc[mi][ni] = z;

  for (int kt = 0; kt < K_DIM; kt += BK) {
    const unsigned short* ag = A + abase + r0 * K_DIM + kt + kof;
    const unsigned short* bg = Bt + bbase + r0 * K_DIM + kt + kof;
    __builtin_amdgcn_global_load_lds((gv_t*)(ag),              (lv_t*)((char*)As + ldsoff),        16, 0, 0);
    __builtin_amdgcn_global_load_lds((gv_t*)(ag + 16 * K_DIM), (lv_t*)((char*)As + ldsoff + 1024), 16, 0, 0);
    __builtin_amdgcn_global_load_lds((gv_t*)(bg),              (lv_t*)((char*)Bs + ldsoff),        16, 0, 0);
    __builtin_amdgcn_global_load_lds((gv_t*)(bg + 16 * K_DIM), (lv_t*)((char*)Bs + ldsoff + 1024), 16, 0, 0);
    __syncthreads();

    bf16x8 af[4], bfr[4];
#pragma unroll
    for (int mi = 0; mi < 4; ++mi) {
      int row = wr * 64 + mi * 16 + lrow;
      af[mi] = *(const bf16x8*)((const char*)As + row * 64 + lkb);
    }
#pragma unroll
    for (int ni = 0; ni < 4; ++ni) {
      int col = wc * 64 + ni * 16 + lrow;
      bfr[ni] = *(const bf16x8*)((const char*)Bs + col * 64 + lkb);
    }
    __syncthreads();

#pragma unroll
    for (int mi = 0; mi < 4; ++mi)
#pragma unroll
      for (int ni = 0; ni < 4; ++ni)
        acc[mi][ni] = __builtin_amdgcn_mfma_f32_16x16x32_bf16(af[mi], bfr[ni], acc[mi][ni], 0, 0, 0);
  }

  // epilogue: C/D layout col = l&15, row = (l>>4)*4 + reg   [HW-verified m89]
  const int row0 = by * BM + wr * 64 + (l >> 4) * 4;
  const int col0 = bx * BN + wc * 64 + lrow;
#pragma unroll
  for (int ni = 0; ni < 4; ++ni) {
    const int col = col0 + ni * 16;
    const float bv = bias[col];
#pragma unroll
    for (int mi = 0; mi < 4; ++mi) {
#pragma unroll
      for (int r = 0; r < 4; ++r) {
        C[(row0 + mi * 16 + r) * N_DIM + col] = acc[mi][ni][r] + bv;
      }
    }
  }
}

// ---------------- fallback (insurance if ws_size too small) ----------------
__global__ void k_fallback(const float* __restrict__ x, const float* __restrict__ scales,
                           const float* __restrict__ bias, const int* __restrict__ w,
                           const int* __restrict__ ci, float* __restrict__ out) {
  const int n = blockIdx.x * 256 + threadIdx.x;
  const int m0 = blockIdx.y * 32;
  float acc[32];
#pragma unroll
  for (int i = 0; i < 32; ++i) acc[i] = 0.f;
  for (int k = 0; k < K_DIM; ++k) {
    int c = ci[k];
    float wv = (float)w[(long)k * N_DIM + n] * scales[(k >> 7) * N_DIM + n];
#pragma unroll 8
    for (int mm = 0; mm < 32; ++mm)
      acc[mm] += x[(long)(m0 + mm) * K_DIM + c] * wv;
  }
  float bv = bias[n];
  for (int mm = 0; mm < 32; ++mm)
    out[(long)(m0 + mm) * N_DIM + n] = acc[mm] + bv;
}

extern "C" void kernel_launch(void* const* d_in, const int* in_sizes, int n_in,
                              void* d_out, int out_size, void* d_ws, size_t ws_size,
                              hipStream_t stream) {
  const float* x      = (const float*)d_in[0];
  const float* scales = (const float*)d_in[1];
  const float* bias   = (const float*)d_in[2];
  const int*   wq     = (const int*)d_in[3];
  const int*   ci     = (const int*)d_in[4];
  // d_in[5] = group_size scalar (128) — hardcoded.
  float* out = (float*)d_out;

  const size_t xb_bytes  = (size_t)M_DIM * K_DIM * 2;  // 64 MiB
  const size_t w2t_bytes = (size_t)N_DIM * K_DIM * 2;  // 32 MiB
  const size_t need = xb_bytes + w2t_bytes + (size_t)K_DIM * 4;

  if (ws_size < need) {
    k_fallback<<<dim3(N_DIM / 256, M_DIM / 32), 256, 0, stream>>>(x, scales, bias, wq, ci, out);
    return;
  }

  unsigned short* xb  = (unsigned short*)d_ws;
  unsigned short* w2t = (unsigned short*)((char*)d_ws + xb_bytes);
  int* pinv           = (int*)((char*)d_ws + xb_bytes + w2t_bytes);

  k_pinv<<<K_DIM / 256, 256, 0, stream>>>(ci, pinv);
  k_cvt<<<2048, 256, 0, stream>>>(x, xb);
  k_w2t<<<dim3(N_DIM / 64, K_DIM / 64), 256, 0, stream>>>(wq, scales, pinv, w2t);
  k_gemm<<<(M_DIM / BM) * (N_DIM / BN), 256, 0, stream>>>(xb, w2t, bias, out);
}

// Round 2
// 324.136 us; speedup vs baseline: 1.3942x; 1.3942x over previous
//
#include <hip/hip_runtime.h>
#include <hip/hip_bf16.h>

#define M_DIM 8192
#define N_DIM 4096
#define K_DIM 4096
#define NT (K_DIM / 32)   // 128 K-tiles of BK=32

typedef __bf16 bf16x8 __attribute__((ext_vector_type(8)));
typedef float f32x4 __attribute__((ext_vector_type(4)));
typedef unsigned short ushort8v __attribute__((ext_vector_type(8)));

typedef const __attribute__((address_space(1))) void gv_t;
typedef __attribute__((address_space(3))) void lv_t;

// round-to-nearest-even fp32 -> bf16
static __device__ __forceinline__ unsigned short f2bf(float f) {
  unsigned u = __builtin_bit_cast(unsigned, f);
  u += 0x7fffu + ((u >> 16) & 1u);
  return (unsigned short)(u >> 16);
}

// ---------------- pre-pass 1: inverse permutation ----------------
__global__ void k_pinv(const int* __restrict__ ci, int* __restrict__ pinv) {
  int k = blockIdx.x * 256 + threadIdx.x;
  if (k < K_DIM) pinv[ci[k]] = k;
}

// ---------------- pre-pass 2: x fp32 -> bf16 ----------------
__global__ void k_cvt(const float* __restrict__ x, unsigned short* __restrict__ xb) {
  const long n4 = (long)M_DIM * K_DIM / 4;
  for (long i = (long)blockIdx.x * 256 + threadIdx.x; i < n4; i += 2048L * 256) {
    float4 v = *(const float4*)(x + i * 4);
    ushort4 o;
    o.x = f2bf(v.x); o.y = f2bf(v.y); o.z = f2bf(v.z); o.w = f2bf(v.w);
    *(ushort4*)(xb + i * 4) = o;
  }
}

// ---------------- pre-pass 3: dequant + permute + transpose ----------------
// w2t[n][c] = (float)w[pinv[c]][n] * scales[pinv[c]>>7][n]  as bf16, [N][K]
__global__ void k_w2t(const int* __restrict__ w, const float* __restrict__ scales,
                      const int* __restrict__ pinv, unsigned short* __restrict__ w2t) {
  __shared__ int tile[64 * 68];
  __shared__ int grp[64];
  __shared__ int krow[64];
  const int n0 = blockIdx.x * 64;
  const int c0 = blockIdx.y * 64;
  const int t = threadIdx.x;
  if (t < 64) {
    int kk = pinv[c0 + t];
    krow[t] = kk;
    grp[t] = kk >> 7;
  }
  __syncthreads();
  {
    const int ci = t >> 2, q = t & 3;
    const int kk = krow[ci];
    const int* src = w + (long)kk * N_DIM + n0 + q * 16;
#pragma unroll
    for (int j = 0; j < 4; ++j) {
      int4 v = *(const int4*)(src + j * 4);
      *(int4*)&tile[ci * 68 + q * 16 + j * 4] = v;
    }
  }
  __syncthreads();
  {
    const int nj = t >> 2, cq = t & 3;
    const int n = n0 + nj;
    unsigned short outv[16];
#pragma unroll
    for (int i = 0; i < 16; ++i) {
      int cii = cq * 16 + i;
      float f = (float)tile[cii * 68 + nj] * scales[grp[cii] * N_DIM + n];
      outv[i] = f2bf(f);
    }
    unsigned short* dst = w2t + (long)n * K_DIM + c0 + cq * 16;
    *(ushort8v*)(dst)     = *(ushort8v*)&outv[0];
    *(ushort8v*)(dst + 8) = *(ushort8v*)&outv[8];
  }
}

// ---------------- main GEMM: 256x256 tile, BK=32, 8 waves, deep pipeline ----------------
// A [M][K] bf16, Bt [N][K] bf16. 3 LDS K-tile buffers, prefetch distance 2,
// counted vmcnt(4) at tile boundaries, XOR-swizzled LDS (sigma: a ^= ((a>>7)&7)<<4),
// raw s_barrier + sched_barrier pins, setprio around MFMA clusters.
__global__ __launch_bounds__(512, 2) void k_gemm(const unsigned short* __restrict__ A,
                                                 const unsigned short* __restrict__ Bt,
                                                 const float* __restrict__ bias,
                                                 float* __restrict__ C) {
  __shared__ __attribute__((aligned(16))) char lds[3 * 32768];   // 96 KiB

  const int bid = blockIdx.x;                  // 512 blocks, 512 % 8 == 0 -> bijective
  const int swz = (bid & 7) * 64 + (bid >> 3); // XCD-aware swizzle
  const int by = swz >> 4;                     // 0..31  M tiles
  const int bx = swz & 15;                     // 0..15  N tiles

  const int tid = threadIdx.x;
  const int l = tid & 63;
  const int w = tid >> 6;       // 0..7
  const int wr = w >> 2;        // 0..1 -> rows wr*128..+128
  const int wc = w & 3;         // 0..3 -> cols wc*64..+64
  const int r4 = l & 15;
  const int kb = (l >> 4) << 4;           // 0,16,32,48 (bytes within 64B k-row)
  const int rmask = (r4 & 14) << 3;       // sigma mask for reads (bits 4-6)

  // ---- staging sources (pre-swizzled global addresses; LDS dest stays linear) ----
  const int wmask = ((tid >> 3) & 7) << 4;
  const char* srcA[2];
  const char* srcB[2];
  {
    const char* Ab = (const char*)A + (size_t)(by * 256) * (K_DIM * 2);
    const char* Bb = (const char*)Bt + (size_t)(bx * 256) * (K_DIM * 2);
#pragma unroll
    for (int j = 0; j < 2; ++j) {
      int L = j * 8192 + tid * 16;
      int lg = L ^ wmask;                 // logical (row,kb) this LDS slot holds
      int row = lg >> 6, kbo = lg & 63;
      srcA[j] = Ab + (size_t)row * (K_DIM * 2) + kbo;
      srcB[j] = Bb + (size_t)row * (K_DIM * 2) + kbo;
    }
  }
  const int stgoff = tid * 16;

  // LDS read base offsets (within a buffer), swizzled
  const int aoff = (((wr * 128 + r4) << 6) + kb) ^ rmask;
  const int boff = (((wc * 64  + r4) << 6) + kb) ^ rmask;

  f32x4 acc[8][4];
  const f32x4 z = {0.f, 0.f, 0.f, 0.f};
#pragma unroll
  for (int mi = 0; mi < 8; ++mi)
#pragma unroll
    for (int ni = 0; ni < 4; ++ni) acc[mi][ni] = z;

  // ---- prologue: stage tiles 0 -> buf0, 1 -> buf1 ----
#pragma unroll
  for (int tt = 0; tt < 2; ++tt) {
    char* ab = lds + tt * 32768;
    char* bb = ab + 16384;
#pragma unroll
    for (int j = 0; j < 2; ++j) {
      __builtin_amdgcn_global_load_lds((gv_t*)(srcA[j] + tt * 64), (lv_t*)(ab + j * 8192 + stgoff), 16, 0, 0);
      __builtin_amdgcn_global_load_lds((gv_t*)(srcB[j] + tt * 64), (lv_t*)(bb + j * 8192 + stgoff), 16, 0, 0);
    }
  }
  asm volatile("s_waitcnt vmcnt(4)" ::: "memory");   // tile 0 landed
  __builtin_amdgcn_sched_barrier(0);
  __builtin_amdgcn_s_barrier();
  __builtin_amdgcn_sched_barrier(0);

  int cur = 0;
  for (int t = 0; t < NT; ++t) {
    char* ab = lds + cur * 32768;
    char* bb = ab + 16384;
    int stg = cur + 2; if (stg >= 3) stg -= 3;       // == (t+2)%3
    char* sab = lds + stg * 32768;
    char* sbb = sab + 16384;
    const bool pf = (t + 2 < NT);
    const long koff = (long)(t + 2) * 64;

    // ======== phase q0: rows wr*128+[0,64) x all 4 ni ========
    bf16x8 af[4], bf[4];
#pragma unroll
    for (int mi = 0; mi < 4; ++mi)
      af[mi] = *(const bf16x8*)(ab + aoff + mi * 1024);
#pragma unroll
    for (int ni = 0; ni < 4; ++ni)
      bf[ni] = *(const bf16x8*)(bb + boff + ni * 1024);
    if (pf) {
      __builtin_amdgcn_global_load_lds((gv_t*)(srcA[0] + koff), (lv_t*)(sab + stgoff), 16, 0, 0);
      __builtin_amdgcn_global_load_lds((gv_t*)(srcA[1] + koff), (lv_t*)(sab + 8192 + stgoff), 16, 0, 0);
    }
    __builtin_amdgcn_sched_barrier(0);
    __builtin_amdgcn_s_barrier();
    __builtin_amdgcn_sched_barrier(0);
    __builtin_amdgcn_s_setprio(1);
#pragma unroll
    for (int mi = 0; mi < 4; ++mi)
#pragma unroll
      for (int ni = 0; ni < 4; ++ni)
        acc[mi][ni] = __builtin_amdgcn_mfma_f32_16x16x32_bf16(af[mi], bf[ni], acc[mi][ni], 0, 0, 0);
    __builtin_amdgcn_s_setprio(0);
    __builtin_amdgcn_sched_barrier(0);
    __builtin_amdgcn_s_barrier();
    __builtin_amdgcn_sched_barrier(0);

    // ======== phase q1: rows wr*128+[64,128) x all 4 ni ========
#pragma unroll
    for (int mi = 0; mi < 4; ++mi)
      af[mi] = *(const bf16x8*)(ab + aoff + 4096 + mi * 1024);
    if (pf) {
      __builtin_amdgcn_global_load_lds((gv_t*)(srcB[0] + koff), (lv_t*)(sbb + stgoff), 16, 0, 0);
      __builtin_amdgcn_global_load_lds((gv_t*)(srcB[1] + koff), (lv_t*)(sbb + 8192 + stgoff), 16, 0, 0);
    }
    __builtin_amdgcn_sched_barrier(0);
    __builtin_amdgcn_s_barrier();
    __builtin_amdgcn_sched_barrier(0);
    __builtin_amdgcn_s_setprio(1);
#pragma unroll
    for (int mi = 0; mi < 4; ++mi)
#pragma unroll
      for (int ni = 0; ni < 4; ++ni)
        acc[4 + mi][ni] = __builtin_amdgcn_mfma_f32_16x16x32_bf16(af[mi], bf[ni], acc[4 + mi][ni], 0, 0, 0);
    __builtin_amdgcn_s_setprio(0);
    // counted drain: everything except this tile's 4 staging loads must have landed
    if (t < NT - 2)       asm volatile("s_waitcnt vmcnt(4)" ::: "memory");
    else if (t == NT - 2) asm volatile("s_waitcnt vmcnt(0)" ::: "memory");
    __builtin_amdgcn_sched_barrier(0);
    __builtin_amdgcn_s_barrier();
    __builtin_amdgcn_sched_barrier(0);

    cur = (cur == 2) ? 0 : cur + 1;
  }

  // ---- epilogue: C/D layout col=l&15, row=(l>>4)*4+reg ----
  const int row0 = by * 256 + wr * 128 + ((l >> 4) << 2);
  const int col0 = bx * 256 + wc * 64 + r4;
#pragma unroll
  for (int ni = 0; ni < 4; ++ni) {
    const int col = col0 + ni * 16;
    const float bv = bias[col];
#pragma unroll
    for (int mi = 0; mi < 8; ++mi) {
#pragma unroll
      for (int r = 0; r < 4; ++r)
        C[(size_t)(row0 + mi * 16 + r) * N_DIM + col] = acc[mi][ni][r] + bv;
    }
  }
}

// ---------------- fallback ----------------
__global__ void k_fallback(const float* __restrict__ x, const float* __restrict__ scales,
                           const float* __restrict__ bias, const int* __restrict__ w,
                           const int* __restrict__ ci, float* __restrict__ out) {
  const int n = blockIdx.x * 256 + threadIdx.x;
  const int m0 = blockIdx.y * 32;
  float acc[32];
#pragma unroll
  for (int i = 0; i < 32; ++i) acc[i] = 0.f;
  for (int k = 0; k < K_DIM; ++k) {
    int c = ci[k];
    float wv = (float)w[(long)k * N_DIM + n] * scales[(k >> 7) * N_DIM + n];
#pragma unroll 8
    for (int mm = 0; mm < 32; ++mm)
      acc[mm] += x[(long)(m0 + mm) * K_DIM + c] * wv;
  }
  float bv = bias[n];
  for (int mm = 0; mm < 32; ++mm)
    out[(long)(m0 + mm) * N_DIM + n] = acc[mm] + bv;
}

extern "C" void kernel_launch(void* const* d_in, const int* in_sizes, int n_in,
                              void* d_out, int out_size, void* d_ws, size_t ws_size,
                              hipStream_t stream) {
  const float* x      = (const float*)d_in[0];
  const float* scales = (const float*)d_in[1];
  const float* bias   = (const float*)d_in[2];
  const int*   wq     = (const int*)d_in[3];
  const int*   ci     = (const int*)d_in[4];
  float* out = (float*)d_out;

  const size_t xb_bytes  = (size_t)M_DIM * K_DIM * 2;
  const size_t w2t_bytes = (size_t)N_DIM * K_DIM * 2;
  const size_t need = xb_bytes + w2t_bytes + (size_t)K_DIM * 4;

  if (ws_size < need) {
    k_fallback<<<dim3(N_DIM / 256, M_DIM / 32), 256, 0, stream>>>(x, scales, bias, wq, ci, out);
    return;
  }

  unsigned short* xb  = (unsigned short*)d_ws;
  unsigned short* w2t = (unsigned short*)((char*)d_ws + xb_bytes);
  int* pinv           = (int*)((char*)d_ws + xb_bytes + w2t_bytes);

  k_pinv<<<K_DIM / 256, 256, 0, stream>>>(ci, pinv);
  k_cvt<<<2048, 256, 0, stream>>>(x, xb);
  k_w2t<<<dim3(N_DIM / 64, K_DIM / 64), 256, 0, stream>>>(wq, scales, pinv, w2t);
  k_gemm<<<(M_DIM / 256) * (N_DIM / 256), 512, 0, stream>>>(xb, w2t, bias, out);
}

// Round 3
// 313.399 us; speedup vs baseline: 1.4420x; 1.0343x over previous
//
#include <hip/hip_runtime.h>
#include <hip/hip_bf16.h>

#define M_DIM 8192
#define N_DIM 4096
#define K_DIM 4096
#define NT (K_DIM / 32)   // 128 K-tiles of BK=32

typedef __bf16 bf16x8 __attribute__((ext_vector_type(8)));
typedef float f32x4 __attribute__((ext_vector_type(4)));
typedef unsigned short ushort8v __attribute__((ext_vector_type(8)));

typedef const __attribute__((address_space(1))) void gv_t;
typedef __attribute__((address_space(3))) void lv_t;

static __device__ __forceinline__ unsigned short f2bf(float f) {
  unsigned u = __builtin_bit_cast(unsigned, f);
  u += 0x7fffu + ((u >> 16) & 1u);
  return (unsigned short)(u >> 16);
}

// ---------------- pre-pass 1: inverse permutation ----------------
__global__ void k_pinv(const int* __restrict__ ci, int* __restrict__ pinv) {
  int k = blockIdx.x * 256 + threadIdx.x;
  if (k < K_DIM) pinv[ci[k]] = k;
}

// ---------------- pre-pass 2: x fp32 -> bf16 ----------------
__global__ void k_cvt(const float* __restrict__ x, unsigned short* __restrict__ xb) {
  const long n4 = (long)M_DIM * K_DIM / 4;
  for (long i = (long)blockIdx.x * 256 + threadIdx.x; i < n4; i += 2048L * 256) {
    float4 v = *(const float4*)(x + i * 4);
    ushort4 o;
    o.x = f2bf(v.x); o.y = f2bf(v.y); o.z = f2bf(v.z); o.w = f2bf(v.w);
    *(ushort4*)(xb + i * 4) = o;
  }
}

// ---------------- pre-pass 3: dequant + permute + transpose ----------------
// w2t[n][c] = (float)w[pinv[c]][n] * scales[pinv[c]>>7][n]  as bf16, [N][K]
__global__ void k_w2t(const int* __restrict__ w, const float* __restrict__ scales,
                      const int* __restrict__ pinv, unsigned short* __restrict__ w2t) {
  __shared__ int tile[64 * 68];
  __shared__ int grp[64];
  __shared__ int krow[64];
  const int n0 = blockIdx.x * 64;
  const int c0 = blockIdx.y * 64;
  const int t = threadIdx.x;
  if (t < 64) {
    int kk = pinv[c0 + t];
    krow[t] = kk;
    grp[t] = kk >> 7;
  }
  __syncthreads();
  {
    const int ci = t >> 2, q = t & 3;
    const int kk = krow[ci];
    const int* src = w + (long)kk * N_DIM + n0 + q * 16;
#pragma unroll
    for (int j = 0; j < 4; ++j) {
      int4 v = *(const int4*)(src + j * 4);
      *(int4*)&tile[ci * 68 + q * 16 + j * 4] = v;
    }
  }
  __syncthreads();
  {
    const int nj = t >> 2, cq = t & 3;
    const int n = n0 + nj;
    unsigned short outv[16];
#pragma unroll
    for (int i = 0; i < 16; ++i) {
      int cii = cq * 16 + i;
      float f = (float)tile[cii * 68 + nj] * scales[grp[cii] * N_DIM + n];
      outv[i] = f2bf(f);
    }
    unsigned short* dst = w2t + (long)n * K_DIM + c0 + cq * 16;
    *(ushort8v*)(dst)     = *(ushort8v*)&outv[0];
    *(ushort8v*)(dst + 8) = *(ushort8v*)&outv[8];
  }
}

// ---------------- main GEMM: 256x256, BK=32, 8 waves, reg-pipelined frags ----------------
// Per tile: q0 {gloadA(t+2); read q1-frags; MFMA q0; vmcnt(2); barB}
//           q1 {gloadB(t+2); read t+1 A-frags; MFMA q1; read t+1 B-frags; barA}
// All ds_read bursts drain under MFMA clusters via compiler-counted lgkmcnt.
__global__ __launch_bounds__(512, 2) void k_gemm(const unsigned short* __restrict__ A,
                                                 const unsigned short* __restrict__ Bt,
                                                 const float* __restrict__ bias,
                                                 float* __restrict__ C) {
  __shared__ __attribute__((aligned(16))) char lds[3 * 32768];   // 96 KiB

  const int bid = blockIdx.x;                  // 512 blocks, %8==0 -> bijective
  const int swz = (bid & 7) * 64 + (bid >> 3);
  const int by = swz >> 4;                     // 0..31
  const int bx = swz & 15;                     // 0..15

  const int tid = threadIdx.x;
  const int l = tid & 63;
  const int w = tid >> 6;
  const int wr = w >> 2;
  const int wc = w & 3;
  const int r4 = l & 15;
  const int kb = (l >> 4) << 4;
  const int rmask = (r4 & 14) << 3;

  // staging sources (pre-swizzled global addrs; LDS dest linear) — verified 0-conflict
  const int wmask = ((tid >> 3) & 7) << 4;
  const char* srcA[2];
  const char* srcB[2];
  {
    const char* Ab = (const char*)A + (size_t)(by * 256) * (K_DIM * 2);
    const char* Bb = (const char*)Bt + (size_t)(bx * 256) * (K_DIM * 2);
#pragma unroll
    for (int j = 0; j < 2; ++j) {
      int L = j * 8192 + tid * 16;
      int lg = L ^ wmask;
      int row = lg >> 6, kbo = lg & 63;
      srcA[j] = Ab + (size_t)row * (K_DIM * 2) + kbo;
      srcB[j] = Bb + (size_t)row * (K_DIM * 2) + kbo;
    }
  }
  const int stgoff = tid * 16;

  const int aoff = (((wr * 128 + r4) << 6) + kb) ^ rmask;
  const int boff = (((wc * 64  + r4) << 6) + kb) ^ rmask;

  f32x4 acc[8][4];
  const f32x4 z = {0.f, 0.f, 0.f, 0.f};
#pragma unroll
  for (int mi = 0; mi < 8; ++mi)
#pragma unroll
    for (int ni = 0; ni < 4; ++ni) acc[mi][ni] = z;

  // ---- prologue: stage A0,B0,A1,B1 (8 loads; queue order matters) ----
#pragma unroll
  for (int tt = 0; tt < 2; ++tt) {
    char* ab = lds + tt * 32768;
    char* bb = ab + 16384;
#pragma unroll
    for (int j = 0; j < 2; ++j)
      __builtin_amdgcn_global_load_lds((gv_t*)(srcA[j] + tt * 64), (lv_t*)(ab + j * 8192 + stgoff), 16, 0, 0);
#pragma unroll
    for (int j = 0; j < 2; ++j)
      __builtin_amdgcn_global_load_lds((gv_t*)(srcB[j] + tt * 64), (lv_t*)(bb + j * 8192 + stgoff), 16, 0, 0);
  }
  asm volatile("s_waitcnt vmcnt(4)" ::: "memory");   // tile 0 landed (A1,B1 still in flight)
  __builtin_amdgcn_sched_barrier(0);
  __builtin_amdgcn_s_barrier();                      // barA(0)
  __builtin_amdgcn_sched_barrier(0);

  // q0 operands of tile 0
  bf16x8 fA[4], fB[4], gA1[4];
#pragma unroll
  for (int mi = 0; mi < 4; ++mi) fA[mi] = *(const bf16x8*)(lds + aoff + mi * 1024);
#pragma unroll
  for (int ni = 0; ni < 4; ++ni) fB[ni] = *(const bf16x8*)(lds + 16384 + boff + ni * 1024);

  int cur = 0;
  for (int t = 0; t < NT; ++t) {
    char* ab = lds + cur * 32768;
    char* bb = ab + 16384;
    int stg = cur + 2; if (stg >= 3) stg -= 3;
    char* sab = lds + stg * 32768;
    char* sbb = sab + 16384;
    int nxt = cur + 1; if (nxt >= 3) nxt -= 3;
    char* nab = lds + nxt * 32768;
    char* nbb = nab + 16384;
    const long koff = (long)(t + 2) * 64;

    // ======== q0 ========
    if (t + 2 < NT) {
      __builtin_amdgcn_global_load_lds((gv_t*)(srcA[0] + koff), (lv_t*)(sab + stgoff), 16, 0, 0);
      __builtin_amdgcn_global_load_lds((gv_t*)(srcA[1] + koff), (lv_t*)(sab + 8192 + stgoff), 16, 0, 0);
    }
    // prefetch q1 A-frags (drain under MFMA q0)
#pragma unroll
    for (int mi = 0; mi < 4; ++mi)
      gA1[mi] = *(const bf16x8*)(ab + aoff + 4096 + mi * 1024);

    __builtin_amdgcn_s_setprio(1);
#pragma unroll
    for (int mi = 0; mi < 4; ++mi)
#pragma unroll
      for (int ni = 0; ni < 4; ++ni)
        acc[mi][ni] = __builtin_amdgcn_mfma_f32_16x16x32_bf16(fA[mi], fB[ni], acc[mi][ni], 0, 0, 0);
    __builtin_amdgcn_s_setprio(0);

    if (t < NT - 2)       asm volatile("s_waitcnt vmcnt(2)" ::: "memory");
    else if (t == NT - 2) asm volatile("s_waitcnt vmcnt(0)" ::: "memory");
    __builtin_amdgcn_sched_barrier(0);
    __builtin_amdgcn_s_barrier();                    // barB: buffer t+1 published
    __builtin_amdgcn_sched_barrier(0);

    // ======== q1 ========
    if (t + 2 < NT) {
      __builtin_amdgcn_global_load_lds((gv_t*)(srcB[0] + koff), (lv_t*)(sbb + stgoff), 16, 0, 0);
      __builtin_amdgcn_global_load_lds((gv_t*)(srcB[1] + koff), (lv_t*)(sbb + 8192 + stgoff), 16, 0, 0);
    }
    // prefetch t+1 q0 A-frags into fA (WAR-safe: q0 MFMA already consumed fA)
    if (t + 1 < NT) {
#pragma unroll
      for (int mi = 0; mi < 4; ++mi)
        fA[mi] = *(const bf16x8*)(nab + aoff + mi * 1024);
    }

    __builtin_amdgcn_s_setprio(1);
#pragma unroll
    for (int mi = 0; mi < 4; ++mi)
#pragma unroll
      for (int ni = 0; ni < 4; ++ni)
        acc[4 + mi][ni] = __builtin_amdgcn_mfma_f32_16x16x32_bf16(gA1[mi], fB[ni], acc[4 + mi][ni], 0, 0, 0);
    __builtin_amdgcn_s_setprio(0);

    // prefetch t+1 B-frags into fB (only after MFMA q1 consumed fB)
    if (t + 1 < NT) {
#pragma unroll
      for (int ni = 0; ni < 4; ++ni)
        fB[ni] = *(const bf16x8*)(nbb + boff + ni * 1024);
    }
    __builtin_amdgcn_sched_barrier(0);
    __builtin_amdgcn_s_barrier();                    // barA(t+1)
    __builtin_amdgcn_sched_barrier(0);

    cur = nxt;
  }

  // ---- epilogue: C/D layout col=l&15, row=(l>>4)*4+reg ----
  const int row0 = by * 256 + wr * 128 + ((l >> 4) << 2);
  const int col0 = bx * 256 + wc * 64 + r4;
#pragma unroll
  for (int ni = 0; ni < 4; ++ni) {
    const int col = col0 + ni * 16;
    const float bv = bias[col];
#pragma unroll
    for (int mi = 0; mi < 8; ++mi) {
#pragma unroll
      for (int r = 0; r < 4; ++r)
        C[(size_t)(row0 + mi * 16 + r) * N_DIM + col] = acc[mi][ni][r] + bv;
    }
  }
}

// ---------------- fallback ----------------
__global__ void k_fallback(const float* __restrict__ x, const float* __restrict__ scales,
                           const float* __restrict__ bias, const int* __restrict__ w,
                           const int* __restrict__ ci, float* __restrict__ out) {
  const int n = blockIdx.x * 256 + threadIdx.x;
  const int m0 = blockIdx.y * 32;
  float acc[32];
#pragma unroll
  for (int i = 0; i < 32; ++i) acc[i] = 0.f;
  for (int k = 0; k < K_DIM; ++k) {
    int c = ci[k];
    float wv = (float)w[(long)k * N_DIM + n] * scales[(k >> 7) * N_DIM + n];
#pragma unroll 8
    for (int mm = 0; mm < 32; ++mm)
      acc[mm] += x[(long)(m0 + mm) * K_DIM + c] * wv;
  }
  float bv = bias[n];
  for (int mm = 0; mm < 32; ++mm)
    out[(long)(m0 + mm) * N_DIM + n] = acc[mm] + bv;
}

extern "C" void kernel_launch(void* const* d_in, const int* in_sizes, int n_in,
                              void* d_out, int out_size, void* d_ws, size_t ws_size,
                              hipStream_t stream) {
  const float* x      = (const float*)d_in[0];
  const float* scales = (const float*)d_in[1];
  const float* bias   = (const float*)d_in[2];
  const int*   wq     = (const int*)d_in[3];
  const int*   ci     = (const int*)d_in[4];
  float* out = (float*)d_out;

  const size_t xb_bytes  = (size_t)M_DIM * K_DIM * 2;
  const size_t w2t_bytes = (size_t)N_DIM * K_DIM * 2;
  const size_t need = xb_bytes + w2t_bytes + (size_t)K_DIM * 4;

  if (ws_size < need) {
    k_fallback<<<dim3(N_DIM / 256, M_DIM / 32), 256, 0, stream>>>(x, scales, bias, wq, ci, out);
    return;
  }

  unsigned short* xb  = (unsigned short*)d_ws;
  unsigned short* w2t = (unsigned short*)((char*)d_ws + xb_bytes);
  int* pinv           = (int*)((char*)d_ws + xb_bytes + w2t_bytes);

  k_pinv<<<K_DIM / 256, 256, 0, stream>>>(ci, pinv);
  k_cvt<<<2048, 256, 0, stream>>>(x, xb);
  k_w2t<<<dim3(N_DIM / 64, K_DIM / 64), 256, 0, stream>>>(wq, scales, pinv, w2t);
  k_gemm<<<(M_DIM / 256) * (N_DIM / 256), 512, 0, stream>>>(xb, w2t, bias, out);
}